// Round 4
// baseline (63755.255 us; speedup 1.0000x reference)
//
#include <hip/hip_runtime.h>
#include <math.h>

// ---------------------------------------------------------------------------
// StateSpaceModel: B=512 T=256 Z=128 X=64 R=1024 HT=HO=1024.
// ALL INPUTS/OUTPUTS ARE FP32 (per reference setup_inputs). GEMMs run on bf16
// MFMA (fp32 accumulate): global fp32 tiles are converted to bf16 during
// LDS staging. Carried state (h, z_t), biases, eps, gate/prop stay fp32.
// Recurrent chain: 4 kernels/step x 256 steps; z_t staged inside d_out
// (out[b,t,0:128]) and overwritten by the fused obs kernel at the end.
// ws: 6.95 MB = h ping-pong (fp32) + trans hidden (bf16) + GP (fp32).
// ---------------------------------------------------------------------------

typedef unsigned short u16;
typedef __bf16 bf16x8 __attribute__((ext_vector_type(8)));
typedef u16    u16x8  __attribute__((ext_vector_type(8)));
typedef float  f32x4  __attribute__((ext_vector_type(4)));

#define DI __device__ __forceinline__
#define LDS_STRIDE 72   // 64 + 8 pad: 16B-aligned, 2-way bank alias (free)

DI u16  f2b(float f){ union{float f; unsigned u;} c; c.f = f;
                      return (u16)((c.u + 0x7fffu + ((c.u>>16)&1u))>>16); }  // RNE
DI float b2f(u16 x){ union{unsigned u; float f;} c; c.u = ((unsigned)x)<<16; return c.f; }
DI float sigm (float x){ return 1.f/(1.f+expf(-x)); }
DI float softp(float x){ return (x>15.f)? x : log1pf(expf(x)); }

DI f32x4 mfma16(bf16x8 a, bf16x8 b, f32x4 c){
  return __builtin_amdgcn_mfma_f32_16x16x32_bf16(a,b,c,0,0,0);
}

// --- staging: 64x64 tile (row stride ld; ld==0 broadcasts row 0) -> LDS bf16
DI void stage64(const float* __restrict__ g, int ld, u16* l){   // fp32 -> bf16
  int t = threadIdx.x;            // 256 threads
#pragma unroll
  for(int i=0;i<2;i++){
    int e = (t + i*256)*8;
    int r = e>>6, c = e&63;
    f32x4 p0 = *(const f32x4*)(g + (size_t)r*ld + c);
    f32x4 p1 = *(const f32x4*)(g + (size_t)r*ld + c + 4);
    u16x8 o;
    o[0]=f2b(p0[0]); o[1]=f2b(p0[1]); o[2]=f2b(p0[2]); o[3]=f2b(p0[3]);
    o[4]=f2b(p1[0]); o[5]=f2b(p1[1]); o[6]=f2b(p1[2]); o[7]=f2b(p1[3]);
    *(u16x8*)(l + r*LDS_STRIDE + c) = o;
  }
}
DI void stage64(const u16* __restrict__ g, int ld, u16* l){     // bf16 copy
  int t = threadIdx.x;
#pragma unroll
  for(int i=0;i<2;i++){
    int e = (t + i*256)*8;
    int r = e>>6, c = e&63;
    *(u16x8*)(l + r*LDS_STRIDE + c) = *(const u16x8*)(g + (size_t)r*ld + c);
  }
}

// load 8 consecutive fp32 weights -> bf16x8 fragment
DI bf16x8 ldw8(const float* __restrict__ g){
  f32x4 p0 = *(const f32x4*)g, p1 = *(const f32x4*)(g+4);
  u16x8 o;
  o[0]=f2b(p0[0]); o[1]=f2b(p0[1]); o[2]=f2b(p0[2]); o[3]=f2b(p0[3]);
  o[4]=f2b(p1[0]); o[5]=f2b(p1[1]); o[6]=f2b(p1[2]); o[7]=f2b(p1[3]);
  return __builtin_bit_cast(bf16x8, o);
}

DI bf16x8 ldfragS(const u16* l, int row, int ko, int stride){
  return __builtin_bit_cast(bf16x8, *(const u16x8*)(l + row*stride + ko));
}
DI bf16x8 ldfrag(const u16* l, int row, int ko){ return ldfragS(l, row, ko, LDS_STRIDE); }

// generic 64x64 block GEMM: acc += A[64,K] @ W[N=64,K]^T  (TA = float or u16)
template<typename TA>
DI void gemm_block(const TA* __restrict__ A, int lda,
                   const float* __restrict__ W, int ldw, int K,
                   u16* lA, u16* lB, f32x4 acc[2][2],
                   int l16, int quad, int wm, int wn)
{
  for(int k0=0;k0<K;k0+=64){
    __syncthreads();
    stage64(A + k0, lda, lA);
    stage64(W + k0, ldw, lB);
    __syncthreads();
#pragma unroll
    for(int kc=0;kc<2;kc++){
      int ko = kc*32 + quad*8;
      bf16x8 a0 = ldfrag(lA, wm*32      + l16, ko);
      bf16x8 a1 = ldfrag(lA, wm*32 + 16 + l16, ko);
      bf16x8 b0 = ldfrag(lB, wn*32      + l16, ko);
      bf16x8 b1 = ldfrag(lB, wn*32 + 16 + l16, ko);
      acc[0][0] = mfma16(a0,b0,acc[0][0]);
      acc[0][1] = mfma16(a0,b1,acc[0][1]);
      acc[1][0] = mfma16(a1,b0,acc[1][0]);
      acc[1][1] = mfma16(a1,b1,acc[1][1]);
    }
  }
}

// ------------------------- init: broadcast h_0 ------------------------------
__global__ __launch_bounds__(256) void k_init(float* __restrict__ hbuf,
                                              const float* __restrict__ h0){
  int idx = blockIdx.x*256 + threadIdx.x;           // 2048 blocks -> 524288
  hbuf[idx] = h0[idx & 1023];
}

// ------------------------- GRU cell (fused) ---------------------------------
// grid (16,8): bx = n-tile over R=1024, by = m-tile over B=512
__global__ __launch_bounds__(256) void k_gru(
  const float* __restrict__ zp, int ldz,
  const float* __restrict__ hin, float* __restrict__ hout,
  const float* __restrict__ wih, const float* __restrict__ bih,
  const float* __restrict__ whh, const float* __restrict__ bhh)
{
  __shared__ u16 lA[64*LDS_STRIDE];
  __shared__ u16 lB[3][64*LDS_STRIDE];
  const int m0 = blockIdx.y*64, n0 = blockIdx.x*64;
  const int lane = threadIdx.x & 63, w = threadIdx.x >> 6;
  const int l16 = lane & 15, quad = lane >> 4, wm = w>>1, wn = w&1;

  f32x4 acc[4][2][2] = {};   // 0=r, 1=z, 2=i_n, 3=h_n

#pragma unroll 1
  for(int ph=0; ph<2; ph++){
    const float* Ab = ph ? hin + (size_t)m0*1024 : zp + (size_t)m0*ldz;
    const float* Wb = ph ? whh + (size_t)n0*1024 : wih + (size_t)n0*128;
    const int lda = ph ? 1024 : ldz;
    const int ldw = ph ? 1024 : 128;
    const int K   = ph ? 1024 : 128;
    const int ai3 = ph ? 3 : 2;
    for(int k0=0;k0<K;k0+=64){
      __syncthreads();
      stage64(Ab + k0, lda, lA);
      stage64(Wb + k0,                     ldw, lB[0]);
      stage64(Wb + (size_t)1024*ldw + k0,  ldw, lB[1]);
      stage64(Wb + (size_t)2048*ldw + k0,  ldw, lB[2]);
      __syncthreads();
#pragma unroll
      for(int kc=0;kc<2;kc++){
        int ko = kc*32 + quad*8;
        bf16x8 a0 = ldfrag(lA, wm*32      + l16, ko);
        bf16x8 a1 = ldfrag(lA, wm*32 + 16 + l16, ko);
#pragma unroll
        for(int s=0;s<3;s++){
          int ai = (s==2) ? ai3 : s;
          bf16x8 b0 = ldfrag(lB[s], wn*32      + l16, ko);
          bf16x8 b1 = ldfrag(lB[s], wn*32 + 16 + l16, ko);
          acc[ai][0][0] = mfma16(a0,b0,acc[ai][0][0]);
          acc[ai][0][1] = mfma16(a0,b1,acc[ai][0][1]);
          acc[ai][1][0] = mfma16(a1,b0,acc[ai][1][0]);
          acc[ai][1][1] = mfma16(a1,b1,acc[ai][1][1]);
        }
      }
    }
  }

#pragma unroll
  for(int mi=0;mi<2;mi++)
#pragma unroll
  for(int ni=0;ni<2;ni++)
#pragma unroll
  for(int i=0;i<4;i++){
    int m = m0 + wm*32 + mi*16 + quad*4 + i;
    int n = n0 + wn*32 + ni*16 + l16;
    float r  = sigm (acc[0][mi][ni][i] + bih[n]      + bhh[n]);
    float z  = sigm (acc[1][mi][ni][i] + bih[n+1024] + bhh[n+1024]);
    float nn = tanhf(acc[2][mi][ni][i] + bih[n+2048]
                     + r*(acc[3][mi][ni][i] + bhh[n+2048]));
    float h  = hin[(size_t)m*1024 + n];
    hout[(size_t)m*1024 + n] = (1.f-z)*nn + z*h;
  }
}

// ------------- trans hidden GEMM: C = act(A @ W^T + b), 3 regions -----------
// n0<1024: tgw relu | n0<2048: tpw relu | else tlw no-act. grid (34,8).
__global__ __launch_bounds__(256) void k_mlp3(
  const float* __restrict__ A,
  const float* __restrict__ W0, const float* __restrict__ B0,
  const float* __restrict__ W1, const float* __restrict__ B1,
  const float* __restrict__ W2, const float* __restrict__ B2,
  u16* __restrict__ C)
{
  __shared__ u16 lA[64*LDS_STRIDE], lB[64*LDS_STRIDE];
  const int m0 = blockIdx.y*64, n0 = blockIdx.x*64;
  const int lane = threadIdx.x & 63, w = threadIdx.x >> 6;
  const int l16 = lane & 15, quad = lane >> 4, wm = w>>1, wn = w&1;
  const float *W, *bias; int act = 1;
  if      (n0 < 1024) { W = W0 + (size_t)n0*1024;        bias = B0 + n0; }
  else if (n0 < 2048) { W = W1 + (size_t)(n0-1024)*1024; bias = B1 + (n0-1024); }
  else                { W = W2 + (size_t)(n0-2048)*1024; bias = B2 + (n0-2048); act = 0; }

  f32x4 acc[2][2] = {};
  gemm_block(A + (size_t)m0*1024, 1024, W, 1024, 1024, lA, lB, acc, l16, quad, wm, wn);

#pragma unroll
  for(int mi=0;mi<2;mi++)
#pragma unroll
  for(int ni=0;ni<2;ni++)
#pragma unroll
  for(int i=0;i<4;i++){
    int m  = m0 + wm*32 + mi*16 + quad*4 + i;
    int cl = wn*32 + ni*16 + l16;
    float v = acc[mi][ni][i] + bias[cl];
    if(act) v = fmaxf(v, 0.f);
    C[(size_t)m*2176 + n0 + cl] = f2b(v);
  }
}

// --------- gate/prop GEMM, fp32 out [512,256]: grid (4,8) -------------------
// n0<128: gate = gate_h @ tghzw^T ; else prop = prop_h @ tphzw^T (A col +1024)
__global__ __launch_bounds__(256) void k_gp(
  const u16* __restrict__ H,
  const float* __restrict__ W0, const float* __restrict__ B0,
  const float* __restrict__ W1, const float* __restrict__ B1,
  float* __restrict__ C)
{
  __shared__ u16 lA[64*LDS_STRIDE], lB[64*LDS_STRIDE];
  const int m0 = blockIdx.y*64, n0 = blockIdx.x*64;
  const int lane = threadIdx.x & 63, w = threadIdx.x >> 6;
  const int l16 = lane & 15, quad = lane >> 4, wm = w>>1, wn = w&1;
  const int reg1 = (n0 >= 128);
  const u16*  A   = H + (size_t)m0*2176 + (reg1 ? 1024 : 0);
  const float* W  = reg1 ? W1 + (size_t)(n0-128)*1024 : W0 + (size_t)n0*1024;
  const float* bias = reg1 ? B1 + (n0-128)            : B0 + n0;

  f32x4 acc[2][2] = {};
  gemm_block(A, 2176, W, 1024, 1024, lA, lB, acc, l16, quad, wm, wn);

#pragma unroll
  for(int mi=0;mi<2;mi++)
#pragma unroll
  for(int ni=0;ni<2;ni++)
#pragma unroll
  for(int i=0;i<4;i++){
    int m  = m0 + wm*32 + mi*16 + quad*4 + i;
    int cl = wn*32 + ni*16 + l16;
    C[(size_t)m*256 + n0 + cl] = acc[mi][ni][i] + bias[cl];
  }
}

// ------------- z_t: scale GEMM (K=128) + reparam; z -> out[b,t,0:128] -------
__global__ __launch_bounds__(256) void k_zt(
  const float* __restrict__ GP, const u16* __restrict__ H,
  const float* __restrict__ sw, const float* __restrict__ sb,
  const float* __restrict__ eps, float* __restrict__ zout, int tstep)
{
  __shared__ u16 lp[64*136];          // relu(proposed) 64x128 bf16, +8 pad
  const int m0 = blockIdx.x*64;
  const int t  = threadIdx.x;
#pragma unroll
  for(int i=0;i<32;i++){
    int e = t + i*256;
    int r = e>>7, c = e&127;
    float p = GP[(size_t)(m0+r)*256 + 128 + c];
    lp[r*136 + c] = f2b(fmaxf(p, 0.f));
  }
  __syncthreads();
  const int lane = t & 63, w = t >> 6, l16 = lane & 15, quad = lane >> 4;
  f32x4 acc[8] = {};
#pragma unroll
  for(int kc=0;kc<4;kc++){
    int ko = kc*32 + quad*8;
    bf16x8 a = ldfragS(lp, w*16+l16, ko, 136);
#pragma unroll
    for(int nf=0;nf<8;nf++){
      bf16x8 b = ldw8(sw + (size_t)(nf*16+l16)*128 + ko);
      acc[nf] = mfma16(a, b, acc[nf]);
    }
  }
#pragma unroll
  for(int nf=0;nf<8;nf++)
#pragma unroll
  for(int i=0;i<4;i++){
    int gm  = m0 + w*16 + quad*4 + i;
    int col = nf*16 + l16;
    float zs  = softp(acc[nf][i] + sb[col]);
    float g   = sigm(GP[(size_t)gm*256 + col]);
    float pv  = GP[(size_t)gm*256 + 128 + col];
    float loc = b2f(H[(size_t)gm*2176 + 2048 + col]);
    float zl  = (1.f-g)*loc + g*pv;
    float e   = eps[(size_t)gm*32768 + (size_t)tstep*128 + col];
    zout[(size_t)gm*32768 + (size_t)tstep*128 + col] = zl + zs*e;
  }
}

// ------------------- FUSED obs branch: one block = 32 rows ------------------
// grid 4096. Reads z (fp32) from out[b,t,0:128], overwrites with x_loc|x_scale.
// LDS: lz 8.7KB + lh 33.3KB + lp 4.6KB = 46.6KB (<64KB/WG).
#define LH_S 520
__global__ __launch_bounds__(256) void k_obs(
  const float* __restrict__ ogw,   const float* __restrict__ ogb,
  const float* __restrict__ oghzw, const float* __restrict__ oghzb,
  const float* __restrict__ opw,   const float* __restrict__ opb,
  const float* __restrict__ ophzw, const float* __restrict__ ophzb,
  const float* __restrict__ olw,   const float* __restrict__ olb,
  const float* __restrict__ osw,   const float* __restrict__ osb,
  float* __restrict__ out)
{
  __shared__ u16 lz[32*136];
  __shared__ u16 lh[32*LH_S];
  __shared__ u16 lp[32*72];
  const int r0 = blockIdx.x*32;
  const int t  = r0 >> 9, b0 = r0 & 511;        // 32 | 512 -> single t per block
  const int tid = threadIdx.x;
  const int lane = tid & 63, w = tid>>6, l16 = lane&15, quad = lane>>4;

  // stage z (32 x 128) fp32 -> bf16
#pragma unroll
  for(int i=0;i<2;i++){
    int ch = tid + i*256;
    int r = ch>>4, c = (ch&15)*8;
    const float* src = out + (size_t)(b0+r)*32768 + (size_t)t*128 + c;
    f32x4 p0 = *(const f32x4*)src, p1 = *(const f32x4*)(src+4);
    u16x8 o;
    o[0]=f2b(p0[0]); o[1]=f2b(p0[1]); o[2]=f2b(p0[2]); o[3]=f2b(p0[3]);
    o[4]=f2b(p1[0]); o[5]=f2b(p1[1]); o[6]=f2b(p1[2]); o[7]=f2b(p1[3]);
    *(u16x8*)(lz + r*136 + c) = o;
  }
  __syncthreads();

  f32x4 accp[2] = {}, accg[2] = {};
  const int col = w*16 + l16;                   // this wave's output column

#pragma unroll 1
  for(int ph=0; ph<2; ph++){                    // 0 = prop path, 1 = gate path
    const float* hw = ph ? ogw   : opw;
    const float* hb = ph ? ogb   : opb;
    const float* zw = ph ? oghzw : ophzw;
    f32x4* acc2     = ph ? accg  : accp;
#pragma unroll 1
    for(int c2=0; c2<2; c2++){                  // hidden cols [c2*512, +512)
      __syncthreads();                          // protect lh from prior readers
      for(int nt = w; nt < 32; nt += 4){
        int n = c2*512 + nt*16 + l16;           // hidden unit = weight row
#pragma unroll
        for(int mi=0; mi<2; mi++){
          f32x4 a = {};
#pragma unroll
          for(int kc=0;kc<4;kc++){
            int ko = kc*32 + quad*8;
            a = mfma16(ldfragS(lz, mi*16+l16, ko, 136),
                       ldw8(hw + (size_t)n*128 + ko), a);
          }
          float bias = hb[n];
#pragma unroll
          for(int i=0;i<4;i++)
            lh[(mi*16+quad*4+i)*LH_S + nt*16 + l16] = f2b(fmaxf(a[i]+bias, 0.f));
        }
      }
      __syncthreads();
      // hz GEMM: accumulate K chunk [c2*512, +512) for output col `col`
#pragma unroll
      for(int mi=0;mi<2;mi++){
        f32x4 a = acc2[mi];
        for(int kc=0;kc<16;kc++){
          int ko = kc*32 + quad*8;
          a = mfma16(ldfragS(lh, mi*16+l16, ko, LH_S),
                     ldw8(zw + (size_t)col*1024 + c2*512 + ko), a);
        }
        acc2[mi] = a;
      }
    }
    if(ph==0){
      float bias = ophzb[col];
#pragma unroll
      for(int mi=0;mi<2;mi++)
#pragma unroll
      for(int i=0;i<4;i++){
        float pv = accp[mi][i] + bias;          // proposed incl. bias
        accp[mi][i] = pv;
        lp[(mi*16+quad*4+i)*72 + col] = f2b(fmaxf(pv, 0.f));
      }
      // lp becomes visible via the barriers inside ph=1's c2 loop
    }
  }

  // loc (K=128, A=lz) and scale (K=64, A=lp) GEMMs for column `col`
  f32x4 accl[2]={}, accs[2]={};
#pragma unroll
  for(int mi=0;mi<2;mi++){
#pragma unroll
    for(int kc=0;kc<4;kc++){
      int ko=kc*32+quad*8;
      accl[mi]=mfma16(ldfragS(lz,mi*16+l16,ko,136),
                      ldw8(olw + (size_t)col*128 + ko), accl[mi]);
    }
#pragma unroll
    for(int kc=0;kc<2;kc++){
      int ko=kc*32+quad*8;
      accs[mi]=mfma16(ldfragS(lp,mi*16+l16,ko,72),
                      ldw8(osw + (size_t)col*64 + ko), accs[mi]);
    }
  }
#pragma unroll
  for(int mi=0;mi<2;mi++)
#pragma unroll
  for(int i=0;i<4;i++){
    int r = mi*16 + quad*4 + i;
    float g  = sigm(accg[mi][i] + oghzb[col]);
    float pv = accp[mi][i];
    float lc = accl[mi][i] + olb[col];
    float xs = softp(accs[mi][i] + osb[col]);
    float xl = (1.f-g)*lc + g*pv;
    size_t o = (size_t)(b0+r)*32768 + (size_t)t*128 + col;
    out[o]      = xl;
    out[o + 64] = xs;
  }
}

// ---------------------------------------------------------------------------
extern "C" void kernel_launch(void* const* d_in, const int* in_sizes, int n_in,
                              void* d_out, int out_size, void* d_ws, size_t ws_size,
                              hipStream_t stream)
{
  (void)in_sizes; (void)n_in; (void)out_size; (void)ws_size;
  const float* eps   = (const float*)d_in[1];
  const float* z0    = (const float*)d_in[2];
  const float* h0    = (const float*)d_in[3];
  const float* gwih  = (const float*)d_in[4];  const float* gbih  = (const float*)d_in[5];
  const float* gwhh  = (const float*)d_in[6];  const float* gbhh  = (const float*)d_in[7];
  const float* tgw   = (const float*)d_in[8];  const float* tgb   = (const float*)d_in[9];
  const float* tghzw = (const float*)d_in[10]; const float* tghzb = (const float*)d_in[11];
  const float* tpw   = (const float*)d_in[12]; const float* tpb   = (const float*)d_in[13];
  const float* tphzw = (const float*)d_in[14]; const float* tphzb = (const float*)d_in[15];
  const float* tlw   = (const float*)d_in[16]; const float* tlb   = (const float*)d_in[17];
  const float* tsw   = (const float*)d_in[18]; const float* tsb   = (const float*)d_in[19];
  const float* ogw   = (const float*)d_in[20]; const float* ogb   = (const float*)d_in[21];
  const float* oghzw = (const float*)d_in[22]; const float* oghzb = (const float*)d_in[23];
  const float* opw   = (const float*)d_in[24]; const float* opb   = (const float*)d_in[25];
  const float* ophzw = (const float*)d_in[26]; const float* ophzb = (const float*)d_in[27];
  const float* olw   = (const float*)d_in[28]; const float* olb   = (const float*)d_in[29];
  const float* osw   = (const float*)d_in[30]; const float* osb   = (const float*)d_in[31];
  float* out = (float*)d_out;

  // ws layout: 6.95 MB total
  char* ws = (char*)d_ws;
  float* hbuf = (float*)ws;                              // 2 x 512x1024 fp32 = 4.19 MB
  u16*   Hbuf = (u16*)(ws + (size_t)2*512*1024*4);       // 512x2176 bf16    = 2.23 MB
  float* GP   = (float*)(ws + (size_t)2*512*1024*4 + (size_t)512*2176*2);  // 0.52 MB

  k_init<<<2048, 256, 0, stream>>>(hbuf, h0);

  for(int t=0; t<256; t++){
    const float* zp  = (t==0) ? z0 : out + (size_t)(t-1)*128;
    const int    ldz = (t==0) ? 0  : 32768;              // ld=0 broadcasts z_0
    const float* hin = hbuf + (size_t)(t&1)*524288;
    float*      hout = hbuf + (size_t)((t+1)&1)*524288;
    k_gru <<<dim3(16,8), 256, 0, stream>>>(zp, ldz, hin, hout, gwih, gbih, gwhh, gbhh);
    k_mlp3<<<dim3(34,8), 256, 0, stream>>>(hout, tgw, tgb, tpw, tpb, tlw, tlb, Hbuf);
    k_gp  <<<dim3(4,8),  256, 0, stream>>>(Hbuf, tghzw, tghzb, tphzw, tphzb, GP);
    k_zt  <<<dim3(8),    256, 0, stream>>>(GP, Hbuf, tsw, tsb, eps, out, t);
  }

  // fused obs: reads z from out slices, overwrites them with x_loc|x_scale
  k_obs<<<4096, 256, 0, stream>>>(ogw, ogb, oghzw, oghzb, opw, opb, ophzw, ophzb,
                                  olw, olb, osw, osb, out);
}